// Round 3
// baseline (4803.661 us; speedup 1.0000x reference)
//
#include <hip/hip_runtime.h>

// LSTM encoder-decoder, MI355X. B=1024, S=256, IN=8, H=512, F=96.
// R9: R6's verified protocol (atomic-RMW barrier poll, post-barrier x load) with ONE
// change: 256 wgs x 512 threads (8 waves = 2/SIMD, still exactly 1 block/CU).
// 16 groups x 64 rows; 16 wgs/group x 128 gate-cols. Wave wv: w=wv&3 (32 gate-cols),
// mh=wv>>2 (32-row half). Per wave: 68 MFMA (2Mx2Nx17K), bw[2][17]=136 VGPRs
// (spill-free, duplicated across the mh pair), acc[2][2]. Co-resident SIMD wave pairs
// interleave GEMM issue with staging waits / barrier spin.
// R7 (512 wgs @2 blocks/CU) deadlocked on residency; R8 added ld_sc0 poll + pre-barrier
// x prefetch and also failed — both novel pieces removed here to isolate the occupancy
// thesis on the known-good synchronization protocol.
// Gates (i,g)/(f,o) in lane pairs l4 <-> l4+8, combined via shfl_xor(8).
// Mode A: XCD-self-organized groups (2/XCD), h via XCD-local L2 (plain stores + sc0
// loads), barrier = TCC atomics. Mode B fallback: agent-scope MALL path.

#define Hh 512
#define K2 544       // 512 h + 8 x + 24 zero pad
#define BATCH 1024
#define SEQ 256
#define FCAST 96
#define Mrows 64
#define SAS 552      // sA stride (f16)
#define SHS 40       // sH stride (f16): 80 B row

typedef _Float16 f16;
typedef _Float16 f16x8 __attribute__((ext_vector_type(8)));
typedef float f32x4 __attribute__((ext_vector_type(4)));

__device__ __forceinline__ float sigf(float v) { return 1.0f / (1.0f + __expf(-v)); }
__device__ __forceinline__ float tanhf_(float v) { return 1.0f - 2.0f / (__expf(2.0f * v) + 1.0f); }

__device__ __forceinline__ f16x8 ld16(const f16* p, bool byp) {
  f16x8 d;
  if (byp) asm volatile("global_load_dwordx4 %0, %1, off sc0 sc1" : "=v"(d) : "v"(p) : "memory");
  else     asm volatile("global_load_dwordx4 %0, %1, off sc0"     : "=v"(d) : "v"(p) : "memory");
  return d;
}
__device__ __forceinline__ void st16(f16* p, f16x8 v, bool byp) {
  if (byp) asm volatile("global_store_dwordx4 %0, %1, off sc0 sc1" :: "v"(p), "v"(v) : "memory");
  else     asm volatile("global_store_dwordx4 %0, %1, off"         :: "v"(p), "v"(v) : "memory");
}
__device__ __forceinline__ int atomic_add_l2(int* p, int v) {
  int old;
  asm volatile("global_atomic_add %0, %1, %2, off sc0\n\ts_waitcnt vmcnt(0)"
               : "=v"(old) : "v"(p), "v"(v) : "memory");
  return old;
}

// ---------------- prep: permute + fp16-convert + fold weights ----------------
// global col n: nslot=n>>7, c=n&127, w=c>>5, cc=c&31, ct=cc>>4, l4=cc&15;
// gate=ct*2+(l4>>3), j=l4&7, unit=nslot*32+w*8+j; source row r=gate*512+unit.
// K: [0,512)=Whh, [512,520)=Wih(enc), [520,544)=0.
__global__ void prep_weights(const float* __restrict__ encWih, const float* __restrict__ encWhh,
                             const float* __restrict__ decWih, const float* __restrict__ decWhh,
                             const float* __restrict__ encBih, const float* __restrict__ encBhh,
                             const float* __restrict__ decBih, const float* __restrict__ decBhh,
                             const float* __restrict__ outW, const float* __restrict__ outB,
                             f16* __restrict__ encT, f16* __restrict__ decPW, f16* __restrict__ decFW,
                             float* __restrict__ bE, float* __restrict__ bP, float* __restrict__ bF) {
  int id = blockIdx.x * 256 + threadIdx.x;
  if (id >= 2048 * 68) return;
  int n = id / 68, c8 = id % 68;
  int nslot = n >> 7, c = n & 127, w = c >> 5, cc = c & 31, ct = cc >> 4, l4v = cc & 15;
  int g = ct * 2 + (l4v >> 3), j = l4v & 7;
  int unit = nslot * 32 + w * 8 + j, r = g * Hh + unit;
  size_t o = (size_t)n * K2 + c8 * 8;
  if (c8 < 64) {
    float dwih = decWih[r];
#pragma unroll
    for (int e = 0; e < 8; ++e) {
      int k = c8 * 8 + e;
      encT[o + e] = (f16)encWhh[(size_t)r * Hh + k];
      float dw = decWhh[(size_t)r * Hh + k];
      decPW[o + e] = (f16)dw;
      decFW[o + e] = (f16)(dw + outW[k] * dwih);
    }
  } else if (c8 == 64) {
#pragma unroll
    for (int e = 0; e < 8; ++e) {
      encT[o + e] = (f16)encWih[r * 8 + e];
      decPW[o + e] = (f16)0.f;
      decFW[o + e] = (f16)0.f;
    }
  } else {
#pragma unroll
    for (int e = 0; e < 8; ++e) {
      encT[o + e] = (f16)0.f;
      decPW[o + e] = (f16)0.f;
      decFW[o + e] = (f16)0.f;
    }
  }
  if (c8 == 0) {
    bE[n] = encBih[r] + encBhh[r];
    float bd = decBih[r] + decBhh[r];
    bP[n] = bd;
    bF[n] = bd + outB[0] * decWih[r];
  }
}

__global__ void init_state(f16* __restrict__ h0, float* __restrict__ out,
                           const float* __restrict__ outB, int* __restrict__ sync) {
  int i = blockIdx.x * 256 + threadIdx.x;
  if (i < BATCH * Hh) h0[i] = (f16)0.f;
  if (i < BATCH * FCAST) out[i] = outB[0];
  if (i < 2048) sync[i] = 0;   // cnt[16*32] + slots[8] + arrive[1]
}

// ---------------- persistent kernel ----------------
__global__ __launch_bounds__(512, 2) void lstm_persist(
    const f16* __restrict__ encT, const f16* __restrict__ decPW, const f16* __restrict__ decFW,
    const float* __restrict__ bE, const float* __restrict__ bP, const float* __restrict__ bF,
    const float* __restrict__ x, f16* __restrict__ h0, f16* __restrict__ h1,
    float* __restrict__ out, const float* __restrict__ outW, int* __restrict__ sync) {
  __shared__ __align__(16) f16 sA[Mrows * SAS];  // 70656 B
  __shared__ __align__(16) f16 sH[Mrows * SHS];  // 5120 B
  __shared__ int sInfo[2];

  int* cnt = sync;            // 16 groups, stride 32 ints
  int* slots = sync + 1024;
  int* arrive = sync + 1032;

  const int T = threadIdx.x;
  const int wv = T >> 6, lane = T & 63, l4 = lane & 15, q = lane >> 4;
  const int w = wv & 3;           // gate-col block of 32
  const int mh = wv >> 2;         // row half: rows [mh*32, mh*32+32)
  const int j = l4 & 7;           // unit within wave's 8
  const bool lo = (l4 < 8);       // lo lanes own gates i,g; hi lanes f,o

  int xcd;
  asm("s_getreg_b32 %0, hwreg(HW_REG_XCC_ID)" : "=s"(xcd));
  xcd &= 7;

  // ---- one-time self-organization (agent scope) ----
  if (T == 0) {
    int r = __hip_atomic_fetch_add(&slots[xcd], 1, __ATOMIC_RELAXED, __HIP_MEMORY_SCOPE_AGENT);
    sInfo[0] = r;
    __hip_atomic_fetch_add(arrive, 1, __ATOMIC_RELAXED, __HIP_MEMORY_SCOPE_AGENT);
    while (__hip_atomic_load(arrive, __ATOMIC_RELAXED, __HIP_MEMORY_SCOPE_AGENT) < 256)
      __builtin_amdgcn_s_sleep(2);
    int ok = 1;
    for (int xx = 0; xx < 8; ++xx)
      ok &= (__hip_atomic_load(&slots[xx], __ATOMIC_RELAXED, __HIP_MEMORY_SCOPE_AGENT) == 32);
    sInfo[1] = ok;
  }
  __syncthreads();
  const int rank = sInfo[0];
  const bool uni = (sInfo[1] != 0);
  int group, nslot;
  if (uni) { group = xcd * 2 + (rank >> 4); nslot = rank & 15; }  // XCD-local group
  else     { group = (int)blockIdx.x >> 4;  nslot = (int)blockIdx.x & 15; }
  const int m0 = group * Mrows, n0 = nslot * 128, u0 = nslot * 32;
  int* myCnt = cnt + group * 32;

  f16x8 bw[2][17];   // 136 VGPRs — fits, no spill
  float bias_r[4];
  float cst[4];      // c-state: lo lanes tile 0 rows, hi lanes tile 1 rows (within mh half)
#pragma unroll
  for (int r = 0; r < 4; ++r) cst[r] = 0.f;

  const int myUnit = u0 + w * 8 + j;

  auto loadB = [&](const f16* WT, const float* bias) {
#pragma unroll
    for (int ct = 0; ct < 2; ++ct) {
      const f16* base = &WT[(size_t)(n0 + w * 32 + ct * 16 + l4) * K2 + q * 8];
#pragma unroll
      for (int ks = 0; ks < 17; ++ks) bw[ct][ks] = *(const f16x8*)(base + ks * 32);
    }
#pragma unroll
    for (int g = 0; g < 4; ++g)
      bias_r[g] = bias[n0 + w * 32 + (g >> 1) * 16 + (g & 1) * 8 + j];
  };

  loadB(encT, bE);
  float ow_r = 0.f;

  for (int s = 0; s < SEQ + FCAST; ++s) {
    const bool enc = s < SEQ;
    if (s == SEQ) {
      loadB(decPW, bP);
      ow_r = outW[myUnit];
    } else if (s == SEQ + 1) {
      loadB(decFW, bF);
    }

    if (s > 0) {
      asm volatile("s_waitcnt vmcnt(0)" ::: "memory");
      __syncthreads();
      if (T == 0) {
        if (uni) {
          atomic_add_l2(myCnt, 1);
          while (atomic_add_l2(myCnt, 0) < 16 * s) __builtin_amdgcn_s_sleep(1);
        } else {
          __hip_atomic_fetch_add(myCnt, 1, __ATOMIC_RELAXED, __HIP_MEMORY_SCOPE_AGENT);
          while (__hip_atomic_load(myCnt, __ATOMIC_RELAXED, __HIP_MEMORY_SCOPE_AGENT) < 16 * s)
            __builtin_amdgcn_s_sleep(2);
        }
      }
      __syncthreads();
    }

    const f16* hin = (s & 1) ? h1 : h0;
    f16* hout = (s & 1) ? h0 : h1;

    // ---- stage A tile 64x512: single batch of 8 loads/thread (512 threads) ----
    {
      f16x8 d[8];
#pragma unroll
      for (int jj = 0; jj < 8; ++jj) {
        int id = T + 512 * jj;
        int row = id >> 6, c8 = (id & 63) * 8;
        d[jj] = ld16(&hin[(size_t)(m0 + row) * Hh + c8], !uni);
      }
      asm volatile("s_waitcnt vmcnt(0)" ::: "memory");
#pragma unroll
      for (int jj = 0; jj < 8; ++jj) {
        int id = T + 512 * jj;
        int row = id >> 6, c8 = (id & 63) * 8;
        *(f16x8*)&sA[row * SAS + c8] = d[jj];
      }
    }
    if (enc && T < Mrows) {
      const float* xp = &x[((size_t)(m0 + T) * SEQ + s) * 8];
      float4 xa = *(const float4*)xp, xb = *(const float4*)(xp + 4);
      f16x8 xv = {(f16)xa.x, (f16)xa.y, (f16)xa.z, (f16)xa.w,
                  (f16)xb.x, (f16)xb.y, (f16)xb.z, (f16)xb.w};
      f16x8 z = {(f16)0.f, (f16)0.f, (f16)0.f, (f16)0.f, (f16)0.f, (f16)0.f, (f16)0.f, (f16)0.f};
      *(f16x8*)&sA[T * SAS + 512] = xv;
      *(f16x8*)&sA[T * SAS + 520] = z;
      *(f16x8*)&sA[T * SAS + 528] = z;
      *(f16x8*)&sA[T * SAS + 536] = z;
    }
    __syncthreads();

    // ---- GEMM: 2 M-tiles (within mh half) x 2 N-tiles x 17 K-steps ----
    f32x4 acc[2][2];
#pragma unroll
    for (int a = 0; a < 2; ++a)
#pragma unroll
      for (int c = 0; c < 2; ++c) acc[a][c] = (f32x4){0.f, 0.f, 0.f, 0.f};

    auto innerK = [&](int ks) {
      int ko = ks * 32 + q * 8;
#pragma unroll
      for (int at = 0; at < 2; ++at) {
        f16x8 af = *(const f16x8*)&sA[(mh * 32 + at * 16 + l4) * SAS + ko];
        acc[at][0] = __builtin_amdgcn_mfma_f32_16x16x32_f16(af, bw[0][ks], acc[at][0], 0, 0, 0);
        acc[at][1] = __builtin_amdgcn_mfma_f32_16x16x32_f16(af, bw[1][ks], acc[at][1], 0, 0, 0);
      }
    };
    if (enc) {
#pragma unroll
      for (int ks = 0; ks < 17; ++ks) innerK(ks);
    } else {
#pragma unroll
      for (int ks = 0; ks < 16; ++ks) innerK(ks);
    }

    // ---- pointwise: lane pair l4 <-> l4+8 exchanges (i,g)<->(f,o) ----
    // lo lane handles tile 0 (rows mh*32+0..15), hi lane tile 1 (rows mh*32+16..31).
#pragma unroll
    for (int r = 0; r < 4; ++r) {
      float xiL = acc[0][0][r], xgL = acc[0][1][r];  // lo owns i,g ; hi owns f,o
      float xiH = acc[1][0][r], xgH = acc[1][1][r];
      // payload = what the partner needs: lo sends its tile-1 vals, hi sends tile-0 vals
      float payload0 = lo ? xiH : xiL;   // ct=0 value partner needs
      float payload1 = lo ? xgH : xgL;   // ct=1 value partner needs
      float pf_recv = __shfl_xor(payload0, 8, 16);
      float po_recv = __shfl_xor(payload1, 8, 16);
      // my gates: lo: i=own ct0(t0), g=own ct1(t0), f=recv0, o=recv1
      //           hi: f=own ct0(t1), o=own ct1(t1), i=recv0, g=recv1
      float gi = lo ? xiL : pf_recv;
      float gf = lo ? pf_recv : xiH;
      float gg_ = lo ? xgL : po_recv;
      float go = lo ? po_recv : xgH;
      float pi = gi + bias_r[0];
      float pf = gf + bias_r[1];
      float pg = gg_ + bias_r[2];
      float po = go + bias_r[3];
      float ig = sigf(pi), fg = sigf(pf), gg = tanhf_(pg), og = sigf(po);
      float cn = fg * cst[r] + ig * gg;
      cst[r] = cn;
      float hn = og * tanhf_(cn);
      int at = lo ? 0 : 1;
      int row = mh * 32 + at * 16 + q * 4 + r;
      sH[row * SHS + w * 8 + j] = (f16)hn;
      if (!enc) {
        float pp = hn * ow_r;
        pp += __shfl_xor(pp, 1, 16);
        pp += __shfl_xor(pp, 2, 16);
        pp += __shfl_xor(pp, 4, 16);
        if (j == 0) atomicAdd(&out[(m0 + row) * FCAST + (s - SEQ)], pp);
      }
    }
    __syncthreads();

    // ---- coalesced h store: 64 rows x 64 B (threads 0..255) ----
    if (T < 256) {
      int row = T >> 2, seg = T & 3;
      f16x8 hv = *(const f16x8*)&sH[row * SHS + seg * 8];
      st16(&hout[(size_t)(m0 + row) * Hh + u0 + seg * 8], hv, !uni);
    }
  }
}

extern "C" void kernel_launch(void* const* d_in, const int* in_sizes, int n_in, void* d_out,
                              int out_size, void* d_ws, size_t ws_size, hipStream_t stream) {
  const float* x = (const float*)d_in[0];
  const float* encWih = (const float*)d_in[1];
  const float* encWhh = (const float*)d_in[2];
  const float* encBih = (const float*)d_in[3];
  const float* encBhh = (const float*)d_in[4];
  const float* decWih = (const float*)d_in[5];
  const float* decWhh = (const float*)d_in[6];
  const float* decBih = (const float*)d_in[7];
  const float* decBhh = (const float*)d_in[8];
  const float* outW = (const float*)d_in[9];
  const float* outB = (const float*)d_in[10];
  float* out = (float*)d_out;

  char* ws = (char*)d_ws;
  f16* encT = (f16*)ws;
  f16* decPW = encT + 2048 * K2;
  f16* decFW = decPW + 2048 * K2;
  f16* h0 = decFW + 2048 * K2;
  f16* h1 = h0 + BATCH * Hh;
  float* bE = (float*)(h1 + BATCH * Hh);
  float* bP = bE + 2048;
  float* bF = bP + 2048;
  int* sync = (int*)(bF + 2048);

  prep_weights<<<544, 256, 0, stream>>>(encWih, encWhh, decWih, decWhh, encBih, encBhh, decBih,
                                        decBhh, outW, outB, encT, decPW, decFW, bE, bP, bF);
  init_state<<<2048, 256, 0, stream>>>(h0, out, outB, sync);
  lstm_persist<<<256, 512, 0, stream>>>(encT, decPW, decFW, bE, bP, bF, x, h0, h1, out, outW, sync);
}

// Round 4
// 4786.338 us; speedup vs baseline: 1.0036x; 1.0036x over previous
//
#include <hip/hip_runtime.h>

// LSTM encoder-decoder, MI355X. B=1024, S=256, IN=8, H=512, F=96.
// R10: R9 with the register cap fixed. R9's __launch_bounds__(512,2) was read by
// hipcc as min-2-BLOCKS/CU (CUDA semantics) -> VGPR capped at 128 < bw[2][17]=136
// -> whole weight array spilled; FETCH_SIZE 31MB -> 5.4GB/dispatch, dur 2.6->4.8ms.
// Fix: amdgpu_waves_per_eu(2) = min 2 waves/EU -> VGPR cap 256, actual ~200, no spill.
// Structure: 256 wgs x 512 threads (8 waves = 2/SIMD, exactly 1 block/CU).
// 16 groups x 64 rows; 16 wgs/group x 128 gate-cols. Wave wv: w=wv&3 (32 gate-cols),
// mh=wv>>2 (32-row half). Per wave: 68 MFMA (2Mx2Nx17K), bw[2][17]=136 VGPRs
// (spill-free, duplicated across the mh pair), acc[2][2]. Co-resident SIMD wave pairs
// interleave GEMM issue with staging waits / barrier spin.
// Gates (i,g)/(f,o) in lane pairs l4 <-> l4+8, combined via shfl_xor(8).
// Mode A: XCD-self-organized groups (2/XCD), h via XCD-local L2 (plain stores + sc0
// loads), barrier = TCC atomics. Mode B fallback: agent-scope MALL path.

#define Hh 512
#define K2 544       // 512 h + 8 x + 24 zero pad
#define BATCH 1024
#define SEQ 256
#define FCAST 96
#define Mrows 64
#define SAS 552      // sA stride (f16)
#define SHS 40       // sH stride (f16): 80 B row

typedef _Float16 f16;
typedef _Float16 f16x8 __attribute__((ext_vector_type(8)));
typedef float f32x4 __attribute__((ext_vector_type(4)));

__device__ __forceinline__ float sigf(float v) { return 1.0f / (1.0f + __expf(-v)); }
__device__ __forceinline__ float tanhf_(float v) { return 1.0f - 2.0f / (__expf(2.0f * v) + 1.0f); }

__device__ __forceinline__ f16x8 ld16(const f16* p, bool byp) {
  f16x8 d;
  if (byp) asm volatile("global_load_dwordx4 %0, %1, off sc0 sc1" : "=v"(d) : "v"(p) : "memory");
  else     asm volatile("global_load_dwordx4 %0, %1, off sc0"     : "=v"(d) : "v"(p) : "memory");
  return d;
}
__device__ __forceinline__ void st16(f16* p, f16x8 v, bool byp) {
  if (byp) asm volatile("global_store_dwordx4 %0, %1, off sc0 sc1" :: "v"(p), "v"(v) : "memory");
  else     asm volatile("global_store_dwordx4 %0, %1, off"         :: "v"(p), "v"(v) : "memory");
}
__device__ __forceinline__ int atomic_add_l2(int* p, int v) {
  int old;
  asm volatile("global_atomic_add %0, %1, %2, off sc0\n\ts_waitcnt vmcnt(0)"
               : "=v"(old) : "v"(p), "v"(v) : "memory");
  return old;
}

// ---------------- prep: permute + fp16-convert + fold weights ----------------
// global col n: nslot=n>>7, c=n&127, w=c>>5, cc=c&31, ct=cc>>4, l4=cc&15;
// gate=ct*2+(l4>>3), j=l4&7, unit=nslot*32+w*8+j; source row r=gate*512+unit.
// K: [0,512)=Whh, [512,520)=Wih(enc), [520,544)=0.
__global__ void prep_weights(const float* __restrict__ encWih, const float* __restrict__ encWhh,
                             const float* __restrict__ decWih, const float* __restrict__ decWhh,
                             const float* __restrict__ encBih, const float* __restrict__ encBhh,
                             const float* __restrict__ decBih, const float* __restrict__ decBhh,
                             const float* __restrict__ outW, const float* __restrict__ outB,
                             f16* __restrict__ encT, f16* __restrict__ decPW, f16* __restrict__ decFW,
                             float* __restrict__ bE, float* __restrict__ bP, float* __restrict__ bF) {
  int id = blockIdx.x * 256 + threadIdx.x;
  if (id >= 2048 * 68) return;
  int n = id / 68, c8 = id % 68;
  int nslot = n >> 7, c = n & 127, w = c >> 5, cc = c & 31, ct = cc >> 4, l4v = cc & 15;
  int g = ct * 2 + (l4v >> 3), j = l4v & 7;
  int unit = nslot * 32 + w * 8 + j, r = g * Hh + unit;
  size_t o = (size_t)n * K2 + c8 * 8;
  if (c8 < 64) {
    float dwih = decWih[r];
#pragma unroll
    for (int e = 0; e < 8; ++e) {
      int k = c8 * 8 + e;
      encT[o + e] = (f16)encWhh[(size_t)r * Hh + k];
      float dw = decWhh[(size_t)r * Hh + k];
      decPW[o + e] = (f16)dw;
      decFW[o + e] = (f16)(dw + outW[k] * dwih);
    }
  } else if (c8 == 64) {
#pragma unroll
    for (int e = 0; e < 8; ++e) {
      encT[o + e] = (f16)encWih[r * 8 + e];
      decPW[o + e] = (f16)0.f;
      decFW[o + e] = (f16)0.f;
    }
  } else {
#pragma unroll
    for (int e = 0; e < 8; ++e) {
      encT[o + e] = (f16)0.f;
      decPW[o + e] = (f16)0.f;
      decFW[o + e] = (f16)0.f;
    }
  }
  if (c8 == 0) {
    bE[n] = encBih[r] + encBhh[r];
    float bd = decBih[r] + decBhh[r];
    bP[n] = bd;
    bF[n] = bd + outB[0] * decWih[r];
  }
}

__global__ void init_state(f16* __restrict__ h0, float* __restrict__ out,
                           const float* __restrict__ outB, int* __restrict__ sync) {
  int i = blockIdx.x * 256 + threadIdx.x;
  if (i < BATCH * Hh) h0[i] = (f16)0.f;
  if (i < BATCH * FCAST) out[i] = outB[0];
  if (i < 2048) sync[i] = 0;   // cnt[16*32] + slots[8] + arrive[1]
}

// ---------------- persistent kernel ----------------
__global__ __attribute__((amdgpu_flat_work_group_size(512, 512), amdgpu_waves_per_eu(2)))
void lstm_persist(
    const f16* __restrict__ encT, const f16* __restrict__ decPW, const f16* __restrict__ decFW,
    const float* __restrict__ bE, const float* __restrict__ bP, const float* __restrict__ bF,
    const float* __restrict__ x, f16* __restrict__ h0, f16* __restrict__ h1,
    float* __restrict__ out, const float* __restrict__ outW, int* __restrict__ sync) {
  __shared__ __align__(16) f16 sA[Mrows * SAS];  // 70656 B
  __shared__ __align__(16) f16 sH[Mrows * SHS];  // 5120 B
  __shared__ int sInfo[2];

  int* cnt = sync;            // 16 groups, stride 32 ints
  int* slots = sync + 1024;
  int* arrive = sync + 1032;

  const int T = threadIdx.x;
  const int wv = T >> 6, lane = T & 63, l4 = lane & 15, q = lane >> 4;
  const int w = wv & 3;           // gate-col block of 32
  const int mh = wv >> 2;         // row half: rows [mh*32, mh*32+32)
  const int j = l4 & 7;           // unit within wave's 8
  const bool lo = (l4 < 8);       // lo lanes own gates i,g; hi lanes f,o

  int xcd;
  asm("s_getreg_b32 %0, hwreg(HW_REG_XCC_ID)" : "=s"(xcd));
  xcd &= 7;

  // ---- one-time self-organization (agent scope) ----
  if (T == 0) {
    int r = __hip_atomic_fetch_add(&slots[xcd], 1, __ATOMIC_RELAXED, __HIP_MEMORY_SCOPE_AGENT);
    sInfo[0] = r;
    __hip_atomic_fetch_add(arrive, 1, __ATOMIC_RELAXED, __HIP_MEMORY_SCOPE_AGENT);
    while (__hip_atomic_load(arrive, __ATOMIC_RELAXED, __HIP_MEMORY_SCOPE_AGENT) < 256)
      __builtin_amdgcn_s_sleep(2);
    int ok = 1;
    for (int xx = 0; xx < 8; ++xx)
      ok &= (__hip_atomic_load(&slots[xx], __ATOMIC_RELAXED, __HIP_MEMORY_SCOPE_AGENT) == 32);
    sInfo[1] = ok;
  }
  __syncthreads();
  const int rank = sInfo[0];
  const bool uni = (sInfo[1] != 0);
  int group, nslot;
  if (uni) { group = xcd * 2 + (rank >> 4); nslot = rank & 15; }  // XCD-local group
  else     { group = (int)blockIdx.x >> 4;  nslot = (int)blockIdx.x & 15; }
  const int m0 = group * Mrows, n0 = nslot * 128, u0 = nslot * 32;
  int* myCnt = cnt + group * 32;

  f16x8 bw[2][17];   // 136 VGPRs — fits under 256 cap, no spill
  float bias_r[4];
  float cst[4];      // c-state: lo lanes tile 0 rows, hi lanes tile 1 rows (within mh half)
#pragma unroll
  for (int r = 0; r < 4; ++r) cst[r] = 0.f;

  const int myUnit = u0 + w * 8 + j;

  auto loadB = [&](const f16* WT, const float* bias) {
#pragma unroll
    for (int ct = 0; ct < 2; ++ct) {
      const f16* base = &WT[(size_t)(n0 + w * 32 + ct * 16 + l4) * K2 + q * 8];
#pragma unroll
      for (int ks = 0; ks < 17; ++ks) bw[ct][ks] = *(const f16x8*)(base + ks * 32);
    }
#pragma unroll
    for (int g = 0; g < 4; ++g)
      bias_r[g] = bias[n0 + w * 32 + (g >> 1) * 16 + (g & 1) * 8 + j];
  };

  loadB(encT, bE);
  float ow_r = 0.f;

  for (int s = 0; s < SEQ + FCAST; ++s) {
    const bool enc = s < SEQ;
    if (s == SEQ) {
      loadB(decPW, bP);
      ow_r = outW[myUnit];
    } else if (s == SEQ + 1) {
      loadB(decFW, bF);
    }

    if (s > 0) {
      asm volatile("s_waitcnt vmcnt(0)" ::: "memory");
      __syncthreads();
      if (T == 0) {
        if (uni) {
          atomic_add_l2(myCnt, 1);
          while (atomic_add_l2(myCnt, 0) < 16 * s) __builtin_amdgcn_s_sleep(1);
        } else {
          __hip_atomic_fetch_add(myCnt, 1, __ATOMIC_RELAXED, __HIP_MEMORY_SCOPE_AGENT);
          while (__hip_atomic_load(myCnt, __ATOMIC_RELAXED, __HIP_MEMORY_SCOPE_AGENT) < 16 * s)
            __builtin_amdgcn_s_sleep(2);
        }
      }
      __syncthreads();
    }

    const f16* hin = (s & 1) ? h1 : h0;
    f16* hout = (s & 1) ? h0 : h1;

    // ---- stage A tile 64x512: single batch of 8 loads/thread (512 threads) ----
    {
      f16x8 d[8];
#pragma unroll
      for (int jj = 0; jj < 8; ++jj) {
        int id = T + 512 * jj;
        int row = id >> 6, c8 = (id & 63) * 8;
        d[jj] = ld16(&hin[(size_t)(m0 + row) * Hh + c8], !uni);
      }
      asm volatile("s_waitcnt vmcnt(0)" ::: "memory");
#pragma unroll
      for (int jj = 0; jj < 8; ++jj) {
        int id = T + 512 * jj;
        int row = id >> 6, c8 = (id & 63) * 8;
        *(f16x8*)&sA[row * SAS + c8] = d[jj];
      }
    }
    if (enc && T < Mrows) {
      const float* xp = &x[((size_t)(m0 + T) * SEQ + s) * 8];
      float4 xa = *(const float4*)xp, xb = *(const float4*)(xp + 4);
      f16x8 xv = {(f16)xa.x, (f16)xa.y, (f16)xa.z, (f16)xa.w,
                  (f16)xb.x, (f16)xb.y, (f16)xb.z, (f16)xb.w};
      f16x8 z = {(f16)0.f, (f16)0.f, (f16)0.f, (f16)0.f, (f16)0.f, (f16)0.f, (f16)0.f, (f16)0.f};
      *(f16x8*)&sA[T * SAS + 512] = xv;
      *(f16x8*)&sA[T * SAS + 520] = z;
      *(f16x8*)&sA[T * SAS + 528] = z;
      *(f16x8*)&sA[T * SAS + 536] = z;
    }
    __syncthreads();

    // ---- GEMM: 2 M-tiles (within mh half) x 2 N-tiles x 17 K-steps ----
    f32x4 acc[2][2];
#pragma unroll
    for (int a = 0; a < 2; ++a)
#pragma unroll
      for (int c = 0; c < 2; ++c) acc[a][c] = (f32x4){0.f, 0.f, 0.f, 0.f};

    auto innerK = [&](int ks) {
      int ko = ks * 32 + q * 8;
#pragma unroll
      for (int at = 0; at < 2; ++at) {
        f16x8 af = *(const f16x8*)&sA[(mh * 32 + at * 16 + l4) * SAS + ko];
        acc[at][0] = __builtin_amdgcn_mfma_f32_16x16x32_f16(af, bw[0][ks], acc[at][0], 0, 0, 0);
        acc[at][1] = __builtin_amdgcn_mfma_f32_16x16x32_f16(af, bw[1][ks], acc[at][1], 0, 0, 0);
      }
    };
    if (enc) {
#pragma unroll
      for (int ks = 0; ks < 17; ++ks) innerK(ks);
    } else {
#pragma unroll
      for (int ks = 0; ks < 16; ++ks) innerK(ks);
    }

    // ---- pointwise: lane pair l4 <-> l4+8 exchanges (i,g)<->(f,o) ----
    // lo lane handles tile 0 (rows mh*32+0..15), hi lane tile 1 (rows mh*32+16..31).
#pragma unroll
    for (int r = 0; r < 4; ++r) {
      float xiL = acc[0][0][r], xgL = acc[0][1][r];  // lo owns i,g ; hi owns f,o
      float xiH = acc[1][0][r], xgH = acc[1][1][r];
      // payload = what the partner needs: lo sends its tile-1 vals, hi sends tile-0 vals
      float payload0 = lo ? xiH : xiL;   // ct=0 value partner needs
      float payload1 = lo ? xgH : xgL;   // ct=1 value partner needs
      float pf_recv = __shfl_xor(payload0, 8, 16);
      float po_recv = __shfl_xor(payload1, 8, 16);
      // my gates: lo: i=own ct0(t0), g=own ct1(t0), f=recv0, o=recv1
      //           hi: f=own ct0(t1), o=own ct1(t1), i=recv0, g=recv1
      float gi = lo ? xiL : pf_recv;
      float gf = lo ? pf_recv : xiH;
      float gg_ = lo ? xgL : po_recv;
      float go = lo ? po_recv : xgH;
      float pi = gi + bias_r[0];
      float pf = gf + bias_r[1];
      float pg = gg_ + bias_r[2];
      float po = go + bias_r[3];
      float ig = sigf(pi), fg = sigf(pf), gg = tanhf_(pg), og = sigf(po);
      float cn = fg * cst[r] + ig * gg;
      cst[r] = cn;
      float hn = og * tanhf_(cn);
      int at = lo ? 0 : 1;
      int row = mh * 32 + at * 16 + q * 4 + r;
      sH[row * SHS + w * 8 + j] = (f16)hn;
      if (!enc) {
        float pp = hn * ow_r;
        pp += __shfl_xor(pp, 1, 16);
        pp += __shfl_xor(pp, 2, 16);
        pp += __shfl_xor(pp, 4, 16);
        if (j == 0) atomicAdd(&out[(m0 + row) * FCAST + (s - SEQ)], pp);
      }
    }
    __syncthreads();

    // ---- coalesced h store: 64 rows x 64 B (threads 0..255) ----
    if (T < 256) {
      int row = T >> 2, seg = T & 3;
      f16x8 hv = *(const f16x8*)&sH[row * SHS + seg * 8];
      st16(&hout[(size_t)(m0 + row) * Hh + u0 + seg * 8], hv, !uni);
    }
  }
}

extern "C" void kernel_launch(void* const* d_in, const int* in_sizes, int n_in, void* d_out,
                              int out_size, void* d_ws, size_t ws_size, hipStream_t stream) {
  const float* x = (const float*)d_in[0];
  const float* encWih = (const float*)d_in[1];
  const float* encWhh = (const float*)d_in[2];
  const float* encBih = (const float*)d_in[3];
  const float* encBhh = (const float*)d_in[4];
  const float* decWih = (const float*)d_in[5];
  const float* decWhh = (const float*)d_in[6];
  const float* decBih = (const float*)d_in[7];
  const float* decBhh = (const float*)d_in[8];
  const float* outW = (const float*)d_in[9];
  const float* outB = (const float*)d_in[10];
  float* out = (float*)d_out;

  char* ws = (char*)d_ws;
  f16* encT = (f16*)ws;
  f16* decPW = encT + 2048 * K2;
  f16* decFW = decPW + 2048 * K2;
  f16* h0 = decFW + 2048 * K2;
  f16* h1 = h0 + BATCH * Hh;
  float* bE = (float*)(h1 + BATCH * Hh);
  float* bP = bE + 2048;
  float* bF = bP + 2048;
  int* sync = (int*)(bF + 2048);

  prep_weights<<<544, 256, 0, stream>>>(encWih, encWhh, decWih, decWhh, encBih, encBhh, decBih,
                                        decBhh, outW, outB, encT, decPW, decFW, bE, bP, bF);
  init_state<<<2048, 256, 0, stream>>>(h0, out, outB, sync);
  lstm_persist<<<256, 512, 0, stream>>>(encT, decPW, decFW, bE, bP, bF, x, h0, h1, out, outW, sync);
}

// Round 6
// 2451.024 us; speedup vs baseline: 1.9599x; 1.9528x over previous
//
#include <hip/hip_runtime.h>

// LSTM encoder-decoder, MI355X. B=1024, S=256, IN=8, H=512, F=96.
// R12: verified R6 geometry + protocol (256 wgs x 256 thr, 1 blk/CU, Mode A XCD
// groups, atomic-RMW convoy barrier) with ONE change: phased staging.
//   issue 16 h-loads (+x loads), vmcnt(8), write rows 0..31, sync,
//   GEMM(at=0,1, ks<16) WHILE rows 32..63 + x in flight, vmcnt(0),
//   write rows 32..63 + x, sync, GEMM remainder.
// Hides ~1 L2 round trip + x latency under 32 MFMA-pairs each step.
//
// !! HARD RULE (3/3 failures): the inter-wg barrier must NEVER be polled with
// plain loads (sc0 or sc0 sc1) -- R8/R11 hung that way. Poll with atomic-RMW
// (atomic_add 0) only; RMWs go through the L2/MALL atomic unit and always
// observe the latest value. 512-thread geometry also banned (R9/R10: Mode-B
// fallback + CU-sharing convoy, FETCH 31MB->5.4GB, 2x regression).
//
// Per wave: bw[2][17]=136 VGPRs weights (spill-free, cap 512 @ launch_bounds(256,1)),
// acc[4][2], d[16] staging live across GEMM phase 1; peak ~285 VGPR.
// Gates (i,g)/(f,o) in lane pairs l4 <-> l4+8, combined via shfl_xor(8).
// Mode A: XCD-self-organized groups, h through XCD-local L2 (plain stores + sc0
// loads), barrier = TCC atomics. Mode B fallback: agent-scope MALL path.

#define Hh 512
#define K2 544       // 512 h + 8 x + 24 zero pad
#define BATCH 1024
#define SEQ 256
#define FCAST 96
#define Mrows 64
#define SAS 552      // sA stride (f16)
#define SHS 40       // sH stride (f16): 80 B row

typedef _Float16 f16;
typedef _Float16 f16x8 __attribute__((ext_vector_type(8)));
typedef float f32x4 __attribute__((ext_vector_type(4)));

__device__ __forceinline__ float sigf(float v) { return 1.0f / (1.0f + __expf(-v)); }
__device__ __forceinline__ float tanhf_(float v) { return 1.0f - 2.0f / (__expf(2.0f * v) + 1.0f); }

__device__ __forceinline__ f16x8 ld16(const f16* p, bool byp) {
  f16x8 d;
  if (byp) asm volatile("global_load_dwordx4 %0, %1, off sc0 sc1" : "=v"(d) : "v"(p) : "memory");
  else     asm volatile("global_load_dwordx4 %0, %1, off sc0"     : "=v"(d) : "v"(p) : "memory");
  return d;
}
__device__ __forceinline__ void st16(f16* p, f16x8 v, bool byp) {
  if (byp) asm volatile("global_store_dwordx4 %0, %1, off sc0 sc1" :: "v"(p), "v"(v) : "memory");
  else     asm volatile("global_store_dwordx4 %0, %1, off"         :: "v"(p), "v"(v) : "memory");
}
__device__ __forceinline__ int atomic_add_l2(int* p, int v) {
  int old;
  asm volatile("global_atomic_add %0, %1, %2, off sc0\n\ts_waitcnt vmcnt(0)"
               : "=v"(old) : "v"(p), "v"(v) : "memory");
  return old;
}

// ---------------- prep: permute + fp16-convert + fold weights ----------------
// global col n: nslot=n>>7, c=n&127, w=c>>5, cc=c&31, ct=cc>>4, l4=cc&15;
// gate=ct*2+(l4>>3), j=l4&7, unit=nslot*32+w*8+j; source row r=gate*512+unit.
// K: [0,512)=Whh, [512,520)=Wih(enc), [520,544)=0.
__global__ void prep_weights(const float* __restrict__ encWih, const float* __restrict__ encWhh,
                             const float* __restrict__ decWih, const float* __restrict__ decWhh,
                             const float* __restrict__ encBih, const float* __restrict__ encBhh,
                             const float* __restrict__ decBih, const float* __restrict__ decBhh,
                             const float* __restrict__ outW, const float* __restrict__ outB,
                             f16* __restrict__ encT, f16* __restrict__ decPW, f16* __restrict__ decFW,
                             float* __restrict__ bE, float* __restrict__ bP, float* __restrict__ bF) {
  int id = blockIdx.x * 256 + threadIdx.x;
  if (id >= 2048 * 68) return;
  int n = id / 68, c8 = id % 68;
  int nslot = n >> 7, c = n & 127, w = c >> 5, cc = c & 31, ct = cc >> 4, l4v = cc & 15;
  int g = ct * 2 + (l4v >> 3), j = l4v & 7;
  int unit = nslot * 32 + w * 8 + j, r = g * Hh + unit;
  size_t o = (size_t)n * K2 + c8 * 8;
  if (c8 < 64) {
    float dwih = decWih[r];
#pragma unroll
    for (int e = 0; e < 8; ++e) {
      int k = c8 * 8 + e;
      encT[o + e] = (f16)encWhh[(size_t)r * Hh + k];
      float dw = decWhh[(size_t)r * Hh + k];
      decPW[o + e] = (f16)dw;
      decFW[o + e] = (f16)(dw + outW[k] * dwih);
    }
  } else if (c8 == 64) {
#pragma unroll
    for (int e = 0; e < 8; ++e) {
      encT[o + e] = (f16)encWih[r * 8 + e];
      decPW[o + e] = (f16)0.f;
      decFW[o + e] = (f16)0.f;
    }
  } else {
#pragma unroll
    for (int e = 0; e < 8; ++e) {
      encT[o + e] = (f16)0.f;
      decPW[o + e] = (f16)0.f;
      decFW[o + e] = (f16)0.f;
    }
  }
  if (c8 == 0) {
    bE[n] = encBih[r] + encBhh[r];
    float bd = decBih[r] + decBhh[r];
    bP[n] = bd;
    bF[n] = bd + outB[0] * decWih[r];
  }
}

__global__ void init_state(f16* __restrict__ h0, float* __restrict__ out,
                           const float* __restrict__ outB, int* __restrict__ sync) {
  int i = blockIdx.x * 256 + threadIdx.x;
  if (i < BATCH * Hh) h0[i] = (f16)0.f;
  if (i < BATCH * FCAST) out[i] = outB[0];
  if (i < 2048) sync[i] = 0;   // cnt[16*32] + slots[8] + arrive[1]
}

// ---------------- persistent kernel ----------------
__global__ __launch_bounds__(256, 1) void lstm_persist(
    const f16* __restrict__ encT, const f16* __restrict__ decPW, const f16* __restrict__ decFW,
    const float* __restrict__ bE, const float* __restrict__ bP, const float* __restrict__ bF,
    const float* __restrict__ x, f16* __restrict__ h0, f16* __restrict__ h1,
    float* __restrict__ out, const float* __restrict__ outW, int* __restrict__ sync) {
  __shared__ __align__(16) f16 sA[Mrows * SAS];  // 70656 B
  __shared__ __align__(16) f16 sH[Mrows * SHS];  // 5120 B
  __shared__ int sInfo[2];

  int* cnt = sync;            // 16 groups, stride 32 ints
  int* slots = sync + 1024;
  int* arrive = sync + 1032;

  const int T = threadIdx.x;
  const int w = T >> 6, lane = T & 63, l4 = lane & 15, q = lane >> 4;
  const int j = l4 & 7;           // unit within wave's 8
  const bool lo = (l4 < 8);       // lo lanes own gates i,g; hi lanes f,o

  int xcd;
  asm("s_getreg_b32 %0, hwreg(HW_REG_XCC_ID)" : "=s"(xcd));
  xcd &= 7;

  // ---- one-time self-organization (agent scope) ----
  if (T == 0) {
    int r = __hip_atomic_fetch_add(&slots[xcd], 1, __ATOMIC_RELAXED, __HIP_MEMORY_SCOPE_AGENT);
    sInfo[0] = r;
    __hip_atomic_fetch_add(arrive, 1, __ATOMIC_RELAXED, __HIP_MEMORY_SCOPE_AGENT);
    while (__hip_atomic_load(arrive, __ATOMIC_RELAXED, __HIP_MEMORY_SCOPE_AGENT) < 256)
      __builtin_amdgcn_s_sleep(2);
    int ok = 1;
    for (int xx = 0; xx < 8; ++xx)
      ok &= (__hip_atomic_load(&slots[xx], __ATOMIC_RELAXED, __HIP_MEMORY_SCOPE_AGENT) == 32);
    sInfo[1] = ok;
  }
  __syncthreads();
  const int rank = sInfo[0];
  const bool uni = (sInfo[1] != 0);
  int group, nslot;
  if (uni) { group = xcd * 2 + (rank >> 4); nslot = rank & 15; }  // XCD-local group
  else     { group = (int)blockIdx.x >> 4;  nslot = (int)blockIdx.x & 15; }
  const int m0 = group * Mrows, n0 = nslot * 128, u0 = nslot * 32;
  int* myCnt = cnt + group * 32;

  f16x8 bw[2][17];   // 136 VGPRs — fits under 512 cap, no spill
  float bias_r[4];
  float cst[2][4];   // c-state: lo lanes rows at{0,1}, hi lanes at{2,3}
#pragma unroll
  for (int a = 0; a < 2; ++a)
#pragma unroll
    for (int r = 0; r < 4; ++r) cst[a][r] = 0.f;

  const int myUnit = u0 + w * 8 + j;

  auto loadB = [&](const f16* WT, const float* bias) {
#pragma unroll
    for (int ct = 0; ct < 2; ++ct) {
      const f16* base = &WT[(size_t)(n0 + w * 32 + ct * 16 + l4) * K2 + q * 8];
#pragma unroll
      for (int ks = 0; ks < 17; ++ks) bw[ct][ks] = *(const f16x8*)(base + ks * 32);
    }
#pragma unroll
    for (int g = 0; g < 4; ++g)
      bias_r[g] = bias[n0 + w * 32 + (g >> 1) * 16 + (g & 1) * 8 + j];
  };

  loadB(encT, bE);
  float ow_r = 0.f;

  for (int s = 0; s < SEQ + FCAST; ++s) {
    const bool enc = s < SEQ;
    if (s == SEQ) {
      loadB(decPW, bP);
      ow_r = outW[myUnit];
    } else if (s == SEQ + 1) {
      loadB(decFW, bF);
    }

    if (s > 0) {
      asm volatile("s_waitcnt vmcnt(0)" ::: "memory");
      __syncthreads();
      if (T == 0) {
        if (uni) {
          atomic_add_l2(myCnt, 1);
          while (atomic_add_l2(myCnt, 0) < 16 * s) __builtin_amdgcn_s_sleep(1);
        } else {
          __hip_atomic_fetch_add(myCnt, 1, __ATOMIC_RELAXED, __HIP_MEMORY_SCOPE_AGENT);
          while (__hip_atomic_load(myCnt, __ATOMIC_RELAXED, __HIP_MEMORY_SCOPE_AGENT) < 16 * s)
            __builtin_amdgcn_s_sleep(2);
        }
      }
      __syncthreads();
    }

    const f16* hin = (s & 1) ? h1 : h0;
    f16* hout = (s & 1) ? h0 : h1;

    // ---- phased staging: issue all 16 h-loads (+x), wait in two halves ----
    f16x8 d[16];
#pragma unroll
    for (int jj = 0; jj < 16; ++jj) {
      int id = T + 256 * jj;
      int row = id >> 6, c8 = (id & 63) * 8;
      d[jj] = ld16(&hin[(size_t)(m0 + row) * Hh + c8], !uni);
    }
    const bool hasx = enc && (T < Mrows);
    float4 xa, xb;
    if (hasx) {
      const float* xp = &x[((size_t)(m0 + T) * SEQ + s) * 8];
      xa = *(const float4*)xp;
      xb = *(const float4*)(xp + 4);
    }
    asm volatile("s_waitcnt vmcnt(8)" ::: "memory");   // oldest 8 h-loads (rows 0..31) done
#pragma unroll
    for (int jj = 0; jj < 8; ++jj) {
      int id = T + 256 * jj;
      int row = id >> 6, c8 = (id & 63) * 8;
      *(f16x8*)&sA[row * SAS + c8] = d[jj];
    }
    __syncthreads();

    // ---- GEMM phase 1: at=0,1 over h-cols (ks 0..15); rows 32..63 + x in flight ----
    f32x4 acc[4][2];
#pragma unroll
    for (int a = 0; a < 4; ++a)
#pragma unroll
      for (int c = 0; c < 2; ++c) acc[a][c] = (f32x4){0.f, 0.f, 0.f, 0.f};

    auto mac = [&](int at, int ks) {
      int ko = ks * 32 + q * 8;
      f16x8 af = *(const f16x8*)&sA[(at * 16 + l4) * SAS + ko];
      acc[at][0] = __builtin_amdgcn_mfma_f32_16x16x32_f16(af, bw[0][ks], acc[at][0], 0, 0, 0);
      acc[at][1] = __builtin_amdgcn_mfma_f32_16x16x32_f16(af, bw[1][ks], acc[at][1], 0, 0, 0);
    };
#pragma unroll
    for (int ks = 0; ks < 16; ++ks) {
      mac(0, ks);
      mac(1, ks);
    }

    // ---- finish staging: rows 32..63 + x cols ----
    asm volatile("s_waitcnt vmcnt(0)" ::: "memory");
#pragma unroll
    for (int jj = 8; jj < 16; ++jj) {
      int id = T + 256 * jj;
      int row = id >> 6, c8 = (id & 63) * 8;
      *(f16x8*)&sA[row * SAS + c8] = d[jj];
    }
    if (hasx) {
      f16x8 xv = {(f16)xa.x, (f16)xa.y, (f16)xa.z, (f16)xa.w,
                  (f16)xb.x, (f16)xb.y, (f16)xb.z, (f16)xb.w};
      f16x8 z = {(f16)0.f, (f16)0.f, (f16)0.f, (f16)0.f, (f16)0.f, (f16)0.f, (f16)0.f, (f16)0.f};
      *(f16x8*)&sA[T * SAS + 512] = xv;
      *(f16x8*)&sA[T * SAS + 520] = z;
      *(f16x8*)&sA[T * SAS + 528] = z;
      *(f16x8*)&sA[T * SAS + 536] = z;
    }
    __syncthreads();

    // ---- GEMM phase 2: x-cols of at=0,1; all of at=2,3 ----
    if (enc) {
      mac(0, 16);
      mac(1, 16);
    }
#pragma unroll
    for (int ks = 0; ks < 16; ++ks) {
      mac(2, ks);
      mac(3, ks);
    }
    if (enc) {
      mac(2, 16);
      mac(3, 16);
    }

    // ---- pointwise: lane pair l4 <-> l4+8 exchanges (i,g)<->(f,o) ----
    // lo lane handles at 0..1 (rows 0..31), hi lane at 2..3 (rows 32..63).
#pragma unroll
    for (int ah = 0; ah < 2; ++ah) {
#pragma unroll
      for (int r = 0; r < 4; ++r) {
        int atL = ah;          // lo's tile
        int atH = ah + 2;      // hi's tile
        float xiL = acc[atL][0][r], xgL = acc[atL][1][r];  // lo owns i,g ; hi owns f,o
        float xiH = acc[atH][0][r], xgH = acc[atH][1][r];
        // payload = what the partner needs
        float payload0 = lo ? xiH : xiL;   // ct=0 value partner needs
        float payload1 = lo ? xgH : xgL;   // ct=1 value partner needs
        float pf_recv = __shfl_xor(payload0, 8, 16);
        float po_recv = __shfl_xor(payload1, 8, 16);
        // my gates: lo: i=own ct0(atL), g=own ct1(atL), f=recv0, o=recv1
        //           hi: f=own ct0(atH), o=own ct1(atH), i=recv0, g=recv1
        float gi = lo ? xiL : pf_recv;
        float gf = lo ? pf_recv : xiH;
        float gg_ = lo ? xgL : po_recv;
        float go = lo ? po_recv : xgH;
        float pi = gi + bias_r[0];
        float pf = gf + bias_r[1];
        float pg = gg_ + bias_r[2];
        float po = go + bias_r[3];
        float ig = sigf(pi), fg = sigf(pf), gg = tanhf_(pg), og = sigf(po);
        float cn = fg * cst[ah][r] + ig * gg;
        cst[ah][r] = cn;
        float hn = og * tanhf_(cn);
        int at = lo ? atL : atH;
        int row = at * 16 + q * 4 + r;
        sH[row * SHS + w * 8 + j] = (f16)hn;
        if (!enc) {
          float pp = hn * ow_r;
          pp += __shfl_xor(pp, 1, 16);
          pp += __shfl_xor(pp, 2, 16);
          pp += __shfl_xor(pp, 4, 16);
          if (j == 0) atomicAdd(&out[(m0 + row) * FCAST + (s - SEQ)], pp);
        }
      }
    }
    __syncthreads();

    // ---- coalesced h store: 64 rows x 64 B ----
    {
      int row = T >> 2, seg = T & 3;
      f16x8 hv = *(const f16x8*)&sH[row * SHS + seg * 8];
      st16(&hout[(size_t)(m0 + row) * Hh + u0 + seg * 8], hv, !uni);
    }
  }
}

extern "C" void kernel_launch(void* const* d_in, const int* in_sizes, int n_in, void* d_out,
                              int out_size, void* d_ws, size_t ws_size, hipStream_t stream) {
  const float* x = (const float*)d_in[0];
  const float* encWih = (const float*)d_in[1];
  const float* encWhh = (const float*)d_in[2];
  const float* encBih = (const float*)d_in[3];
  const float* encBhh = (const float*)d_in[4];
  const float* decWih = (const float*)d_in[5];
  const float* decWhh = (const float*)d_in[6];
  const float* decBih = (const float*)d_in[7];
  const float* decBhh = (const float*)d_in[8];
  const float* outW = (const float*)d_in[9];
  const float* outB = (const float*)d_in[10];
  float* out = (float*)d_out;

  char* ws = (char*)d_ws;
  f16* encT = (f16*)ws;
  f16* decPW = encT + 2048 * K2;
  f16* decFW = decPW + 2048 * K2;
  f16* h0 = decFW + 2048 * K2;
  f16* h1 = h0 + BATCH * Hh;
  float* bE = (float*)(h1 + BATCH * Hh);
  float* bP = bE + 2048;
  float* bF = bP + 2048;
  int* sync = (int*)(bF + 2048);

  prep_weights<<<544, 256, 0, stream>>>(encWih, encWhh, decWih, decWhh, encBih, encBhh, decBih,
                                        decBhh, outW, outB, encT, decPW, decFW, bE, bP, bF);
  init_state<<<2048, 256, 0, stream>>>(h0, out, outB, sync);
  lstm_persist<<<256, 256, 0, stream>>>(encT, decPW, decFW, bE, bP, bF, x, h0, h1, out, outW, sync);
}